// Round 6
// baseline (857.111 us; speedup 1.0000x reference)
//
#include <hip/hip_runtime.h>
#include <cstddef>

#define NPTS   40000
#define NGRP   256
#define GSZ    64
#define FDIM   768
#define BATCH  2

// ---- FPS geometry (identical to proven round-4 kernel) ----
#define FPS_BPB    32                  // blocks per batch
#define FPS_NBLK   (FPS_BPB * BATCH)   // 64
#define FPS_PPB    (NPTS / FPS_BPB)    // 1250
#define FPS_PPT    20                  // ceil(1250/64)
#define FPS_ITERS  (NGRP - 1)

#define W_NBLK     (BATCH * NGRP)      // 512 worker blocks (one per center)
#define GRID_BLK   (FPS_NBLK + W_NBLK) // 576
#define NCHUNK     (NPTS / 64)         // 625

// key: high 48 bits = f64 bits of dist (>=0, monotone as integer),
// low 16 bits = 0xFFFF - idx so larger key == smaller idx on tie. Never zero.
__device__ __forceinline__ unsigned long long fps_key(double v, int idx) {
    unsigned long long bits = (unsigned long long)__double_as_longlong(v);
    return (bits & 0xFFFFFFFFFFFF0000ull) | (unsigned long long)(0xFFFFu - (unsigned)idx);
}
// key for "min dist, tie -> min index": low 16 bits = idx.
__device__ __forceinline__ unsigned long long knn_key(double v, int idx) {
    unsigned long long bits = (unsigned long long)__double_as_longlong(v);
    return (bits & 0xFFFFFFFFFFFF0000ull) | (unsigned long long)(unsigned)idx;
}

__global__ void __launch_bounds__(256) fused_kernel(
    const float* __restrict__ xyz,            // (2, NPTS, 3)
    const float* __restrict__ fts,            // (2, NPTS, 768)
    const int*   __restrict__ valid,          // (2, NPTS)
    float* __restrict__ all_fts,              // (2,256,768) in d_out
    float* __restrict__ mask,                 // (2,256)     in d_out
    float* __restrict__ centers,              // (2,256,3)   in d_out
    unsigned long long* __restrict__ keys,    // [255][64] mailbox, pre-zeroed
    unsigned int* __restrict__ flags)         // [512] per-center ready flags, pre-zeroed
{
    const int bid = blockIdx.x;
    const int tid = threadIdx.x;

    if (bid < FPS_NBLK) {
        // ================= FPS role: single wave per block (round-4 proven) ====
        if (tid >= 64) return;               // waves 1..3 exit; no barriers below
        const int lane = tid;
        const int b    = bid >> 5;
        const int lb   = bid & 31;
        const float* __restrict__ X = xyz + (size_t)b * NPTS * 3;
        const int base  = lb * FPS_PPB;
        const int gbase = base + lane;

        double px[FPS_PPT], py[FPS_PPT], pz[FPS_PPT], dist[FPS_PPT];
#pragma unroll
        for (int j = 0; j < FPS_PPT; ++j) {
            int loc = lane + j * 64;
            bool ok = loc < FPS_PPB;
            int i   = base + (ok ? loc : 0);
            px[j]   = (double)X[i * 3 + 0];
            py[j]   = (double)X[i * 3 + 1];
            pz[j]   = (double)X[i * 3 + 2];
            dist[j] = ok ? 1e18 : -1.0;      // sentinels never win (valid dists >= 0)
        }

        double cx = (double)X[0], cy = (double)X[1], cz = (double)X[2];
        if (lb == 0 && lane == 0) {
            centers[(size_t)(b * NGRP) * 3 + 0] = X[0];
            centers[(size_t)(b * NGRP) * 3 + 1] = X[1];
            centers[(size_t)(b * NGRP) * 3 + 2] = X[2];
            __hip_atomic_store(&flags[b * NGRP], 1u,
                               __ATOMIC_RELEASE, __HIP_MEMORY_SCOPE_AGENT);
        }

        for (int it = 0; it < FPS_ITERS; ++it) {
            double bd = -2.0; int bj = 0;
#pragma unroll
            for (int j = 0; j < FPS_PPT; ++j) {
                double dx = px[j] - cx, dy = py[j] - cy, dz = pz[j] - cz;
                double d  = fma(dz, dz, fma(dy, dy, dx * dx));
                double nd = dist[j] < d ? dist[j] : d;
                dist[j] = nd;
                bool better = nd > bd;       // strict > keeps smallest j (= smallest idx)
                bd = better ? nd : bd;
                bj = better ? j  : bj;
            }
            unsigned long long key = fps_key(bd, gbase + (bj << 6));
#pragma unroll
            for (int off = 32; off >= 1; off >>= 1) {
                unsigned long long o = __shfl_xor(key, off, 64);
                key = o > key ? o : key;
            }
            if (lane == 0)
                __hip_atomic_store(&keys[it * FPS_NBLK + bid], key,
                                   __ATOMIC_RELAXED, __HIP_MEMORY_SCOPE_AGENT);

            // 32 lanes poll the batch's 32 fresh slots (one coalesced round)
            unsigned long long pk = 0;
            if (lane < FPS_BPB) {
                const unsigned long long* sp = &keys[it * FPS_NBLK + b * FPS_BPB + lane];
                do {
                    pk = __hip_atomic_load(sp, __ATOMIC_RELAXED, __HIP_MEMORY_SCOPE_AGENT);
                } while (pk == 0ull);
            }
            unsigned long long g = pk;
#pragma unroll
            for (int off = 16; off >= 1; off >>= 1) {
                unsigned long long o = __shfl_xor(g, off, 64);
                g = o > g ? o : g;
            }
            g = __shfl(g, 0, 64);
            int widx = 0xFFFF - (int)(g & 0xFFFFull);
            float wx = X[widx * 3 + 0], wy = X[widx * 3 + 1], wz = X[widx * 3 + 2];
            cx = (double)wx; cy = (double)wy; cz = (double)wz;
            if (lb == 0 && lane == 0) {
                centers[(size_t)(b * NGRP + it + 1) * 3 + 0] = wx;
                centers[(size_t)(b * NGRP + it + 1) * 3 + 1] = wy;
                centers[(size_t)(b * NGRP + it + 1) * 3 + 2] = wz;
                __hip_atomic_store(&flags[b * NGRP + it + 1], 1u,
                                   __ATOMIC_RELEASE, __HIP_MEMORY_SCOPE_AGENT);
            }
        }
        return;
    }

    // ================= Worker role: one block per center (knn + agg + mask) ====
    const int c    = bid - FPS_NBLK;     // [0, 512)
    const int b    = c >> 8;
    const int wid  = tid >> 6;
    const int lane = tid & 63;
    const float* __restrict__ X = xyz + (size_t)b * NPTS * 3;

    // wait until this center is published (relaxed polls, single acquire fence)
    {
        const unsigned int* fp = &flags[c];
        while (__hip_atomic_load(fp, __ATOMIC_RELAXED, __HIP_MEMORY_SCOPE_AGENT) == 0u)
            __builtin_amdgcn_s_sleep(64);
        __builtin_amdgcn_fence(__ATOMIC_ACQUIRE, "agent");
    }

    const double cx = (double)centers[(size_t)c * 3 + 0];
    const double cy = (double)centers[(size_t)c * 3 + 1];
    const double cz = (double)centers[(size_t)c * 3 + 2];

    // wave `wid` owns chunks s ≡ wid (mod 4); its first chunk seeds the slots
    unsigned long long slot;
    {
        int i = wid * 64 + lane;
        float x = X[i * 3 + 0], y = X[i * 3 + 1], z = X[i * 3 + 2];
        double dx = (double)x - cx, dy = (double)y - cy, dz = (double)z - cz;
        slot = knn_key(dx * dx + dy * dy + dz * dz, i);
    }
    unsigned long long tau = slot;
#pragma unroll
    for (int off = 32; off >= 1; off >>= 1) {
        unsigned long long o = __shfl_xor(tau, off, 64);
        tau = o > tau ? o : tau;
    }

    // depth-2 software prefetch over this wave's chunk list
    float ax, ay, az, bx, by, bz;
    {
        int ia = (wid + 4) * 64 + lane;
        ax = X[ia * 3 + 0]; ay = X[ia * 3 + 1]; az = X[ia * 3 + 2];
        int sb = wid + 8 < NCHUNK ? wid + 8 : NCHUNK - 1;
        int ib = sb * 64 + lane;
        bx = X[ib * 3 + 0]; by = X[ib * 3 + 1]; bz = X[ib * 3 + 2];
    }
    for (int s = wid + 4; s < NCHUNK; s += 4) {
        float x = ax, y = ay, z = az;
        ax = bx; ay = by; az = bz;
        int sp = s + 8 < NCHUNK ? s + 8 : NCHUNK - 1;
        int ip = sp * 64 + lane;
        bx = X[ip * 3 + 0]; by = X[ip * 3 + 1]; bz = X[ip * 3 + 2];

        int i = s * 64 + lane;
        double dx = (double)x - cx, dy = (double)y - cy, dz = (double)z - cz;
        unsigned long long key = knn_key(dx * dx + dy * dy + dz * dz, i);

        unsigned long long cand = __ballot(key < tau);
        while (cand) {
            int l = __ffsll(cand) - 1;
            cand &= cand - 1;
            unsigned long long kc = __shfl(key, l, 64);
            if (kc < tau) {
                unsigned long long om = __ballot(slot == tau);
                int owner = __ffsll(om) - 1;
                if (lane == owner) slot = kc;
                unsigned long long t = slot;
#pragma unroll
                for (int off = 32; off >= 1; off >>= 1) {
                    unsigned long long o = __shfl_xor(t, off, 64);
                    t = o > t ? o : t;
                }
                tau = t;
            }
        }
    }

    // merge the 4 local top-64 sets exactly: bitonic sort of 256 keys in LDS
    __shared__ unsigned long long skey[256];
    __shared__ int s_nbr[GSZ];
    skey[tid] = slot;
    __syncthreads();
#pragma unroll
    for (int k = 2; k <= 256; k <<= 1) {
        for (int j = k >> 1; j > 0; j >>= 1) {
            int ixj = tid ^ j;
            if (ixj > tid) {
                unsigned long long a = skey[tid], bb = skey[ixj];
                bool up = ((tid & k) == 0);
                if ((a > bb) == up) { skey[tid] = bb; skey[ixj] = a; }
            }
            __syncthreads();
        }
    }

    if (wid == 0) {
        int idx = (int)(skey[lane] & 0xFFFFull);
        s_nbr[lane] = idx;
        int v = valid[b * NPTS + idx];
        unsigned long long vb = __ballot(v != 0);
        if (lane == 0) mask[c] = vb ? 1.0f : 0.0f;
    }
    __syncthreads();

    // fused aggregation: 256 threads cover 768 dims (3 each), 6 acc chains
    const float* __restrict__ F = fts + (size_t)b * NPTS * FDIM;
    float a0 = 0.f, a1 = 0.f, a2 = 0.f, b0 = 0.f, b1 = 0.f, b2 = 0.f;
#pragma unroll 1
    for (int j = 0; j < GSZ; j += 2) {
        const float* r0 = F + (size_t)s_nbr[j]     * FDIM;
        const float* r1 = F + (size_t)s_nbr[j + 1] * FDIM;
        a0 += r0[tid];       b0 += r1[tid];
        a1 += r0[tid + 256]; b1 += r1[tid + 256];
        a2 += r0[tid + 512]; b2 += r1[tid + 512];
    }
    float* o = all_fts + (size_t)c * FDIM;
    o[tid]       = (a0 + b0) * 0.015625f;
    o[tid + 256] = (a1 + b1) * 0.015625f;
    o[tid + 512] = (a2 + b2) * 0.015625f;
}

extern "C" void kernel_launch(void* const* d_in, const int* in_sizes, int n_in,
                              void* d_out, int out_size, void* d_ws, size_t ws_size,
                              hipStream_t stream) {
    const float* xyz   = (const float*)d_in[0];
    const float* fts   = (const float*)d_in[1];
    const int*   valid = (const int*)d_in[2];

    float* out     = (float*)d_out;
    float* all_fts = out;                                  // (2,256,768)
    float* mask    = out + (size_t)BATCH * NGRP * FDIM;    // (2,256)
    float* centers = mask + (size_t)BATCH * NGRP;          // (2,256,3)

    unsigned long long* keys  = (unsigned long long*)d_ws;         // 255*64*8 = 130560 B
    unsigned int*       flags = (unsigned int*)((char*)d_ws + 130560); // 512*4 = 2048 B

    // mailbox + flags must be zero at the start of EVERY call
    hipMemsetAsync(d_ws, 0, 132608, stream);

    fused_kernel<<<dim3(GRID_BLK), dim3(256), 0, stream>>>(
        xyz, fts, valid, all_fts, mask, centers, keys, flags);
}